// Round 1
// baseline (268.429 us; speedup 1.0000x reference)
//
#include <hip/hip_runtime.h>
#include <hip/hip_bf16.h>
#include <math.h>

#define K_B 32
#define NRELD 16
#define PSZ 128
#define HID 768

// -------------------------------------------------------------------------
// K0: ranks, unique labels, masks, active counts, owner map, zero prop/loss
// -------------------------------------------------------------------------
__global__ __launch_bounds__(512) void k_setup(const int* __restrict__ labels,
        const int* __restrict__ rel, int* __restrict__ inv, int* __restrict__ lu,
        int* __restrict__ rowflag, int* __restrict__ batchflag,
        int* __restrict__ total, int* __restrict__ rowOwner,
        float* __restrict__ nAct, float* __restrict__ lossAcc,
        float* __restrict__ prop)
{
    __shared__ int lab[32], rankS[32], luS[32], ownS[128];
    __shared__ int rowflagS[512], cntS[512], bfS[32], totS;
    int t = threadIdx.x;
    if (t < 32) lab[t] = labels[t];
    __syncthreads();
    if (t < 32) {
        int r = 0;
        for (int j = 0; j < 32; ++j) r += (lab[j] < lab[t]);
        rankS[t] = r; inv[t] = r;
    }
    if (t < 128) ownS[t] = -1;
    __syncthreads();
    if (t < 32) luS[rankS[t]] = lab[t];
    __syncthreads();
    if (t < 32) { lu[t] = luS[t]; ownS[luS[t]] = t; }
    __syncthreads();
    if (t < 128) rowOwner[t] = ownS[t];
    // row sums & active counts (over rel_k[k] = rel[inv[k]])
    {
        int k = t >> 4, i = t & 15;
        const int* rp = rel + ((size_t)rankS[k] * NRELD + i) * PSZ;
        int s = 0, c = 0;
        for (int j = 0; j < PSZ; ++j) { int v_ = rp[j]; s += v_; c += (v_ != PSZ); }
        rowflagS[t] = (s > 0); cntS[t] = c;
        rowflag[t] = (s > 0);
    }
    __syncthreads();
    if (t < 32) {
        int b = 0;
        for (int i = 0; i < 16; ++i) b |= rowflagS[t*16 + i];
        bfS[t] = b; batchflag[t] = b;
    }
    __syncthreads();
    if (t == 0) {
        int tt = 0;
        for (int k = 0; k < 32; ++k) tt |= bfS[k];
        totS = tt; total[0] = tt; lossAcc[0] = 0.f;
    }
    __syncthreads();
    if (t < 32) {
        float n = 0.f;
        if (totS && bfS[t])
            for (int i = 0; i < 16; ++i)
                if (rowflagS[t*16 + i]) n += (float)cntS[t*16 + i];
        nAct[t] = n;
    }
    for (int idx = t; idx < K_B*HID; idx += 512) prop[idx] = 0.f;
}

// -------------------------------------------------------------------------
// K1: w[k,r,h] = sum over active j of P0[head[k,r,j]][h]
// -------------------------------------------------------------------------
__global__ __launch_bounds__(192) void k_w(const float* __restrict__ P0,
        const int* __restrict__ rel, const int* __restrict__ inv,
        const int* __restrict__ rowflag, const int* __restrict__ batchflag,
        const int* __restrict__ total, float* __restrict__ w)
{
    int k = blockIdx.x, r = blockIdx.y, t = threadIdx.x;
    __shared__ int ids[128];
    __shared__ int flagS;
    if (t < 128) ids[t] = rel[((size_t)inv[k]*NRELD + r)*PSZ + t];
    if (t == 0) flagS = total[0] && batchflag[k] && rowflag[k*NRELD + r];
    __syncthreads();
    float4 acc = {0.f, 0.f, 0.f, 0.f};
    if (flagS) {
        for (int j = 0; j < 128; ++j) {
            int id = ids[j];             // wave-uniform branch (LDS scalar)
            if (id != PSZ) {
                float4 pv = *(const float4*)&P0[(size_t)id*HID + t*4];
                acc.x += pv.x; acc.y += pv.y; acc.z += pv.z; acc.w += pv.w;
            }
        }
    }
    *(float4*)&w[((size_t)k*NRELD + r)*HID + t*4] = acc;
}

// -------------------------------------------------------------------------
// K2: v[k,r,h] = sum_g rel[r,h,g] * P0[lu[k]][g]
// grid (16 r, 24 htiles of 32), 256 thr: k = t&31, hp = t>>5 (4 rows each)
// -------------------------------------------------------------------------
__global__ __launch_bounds__(256) void k_v(const float* __restrict__ rel,
        const float* __restrict__ P0, const int* __restrict__ lu,
        float* __restrict__ v)
{
    int r = blockIdx.x, h0 = blockIdx.y*32, t = threadIdx.x;
    int k = t & 31, hp = t >> 5;
    __shared__ float ptS[32][33];
    __shared__ int luS[32];
    if (t < 32) luS[t] = lu[t];
    float acc[4] = {0.f, 0.f, 0.f, 0.f};
    for (int c = 0; c < 24; ++c) {
        int g0 = c*32;
        __syncthreads();
        {
            int kk = t >> 3, q = t & 7;
            float4 pv = *(const float4*)&P0[(size_t)luS[kk]*HID + g0 + q*4];
            ptS[kk][q*4+0] = pv.x; ptS[kk][q*4+1] = pv.y;
            ptS[kk][q*4+2] = pv.z; ptS[kk][q*4+3] = pv.w;
        }
        __syncthreads();
        float pr[32];
        #pragma unroll
        for (int g = 0; g < 32; ++g) pr[g] = ptS[k][g];
        #pragma unroll
        for (int m = 0; m < 4; ++m) {
            int h = h0 + hp*4 + m;
            const float4* rp = (const float4*)&rel[((size_t)r*HID + h)*HID + g0];
            #pragma unroll
            for (int q = 0; q < 8; ++q) {
                float4 rv = rp[q];
                acc[m] += rv.x*pr[q*4+0] + rv.y*pr[q*4+1]
                        + rv.z*pr[q*4+2] + rv.w*pr[q*4+3];
            }
        }
    }
    #pragma unroll
    for (int m = 0; m < 4; ++m)
        v[((size_t)k*NRELD + r)*HID + h0 + hp*4 + m] = acc[m];
}

// -------------------------------------------------------------------------
// K3: prop[k,g] += sum_{h in chunk} w[k,r,h] * rel[r,h,g]
// grid (16 r, 6 gtiles of 128, 4 hslabs of 192), 256 thr
// -------------------------------------------------------------------------
__global__ __launch_bounds__(256) void k_prop(const float* __restrict__ rel,
        const float* __restrict__ w, float* __restrict__ prop)
{
    int r = blockIdx.x, g0 = blockIdx.y*128, hbase = blockIdx.z*192;
    int t = threadIdx.x, gi = t & 31, kq = t >> 5;
    __shared__ float wS[32][33];
    float4 acc[4] = {};
    for (int hc = 0; hc < 6; ++hc) {
        int h0c = hbase + hc*32;
        __syncthreads();
        {
            int kk = t >> 3, q = t & 7;
            float4 wv = *(const float4*)&w[((size_t)kk*NRELD + r)*HID + h0c + q*4];
            wS[kk][q*4+0] = wv.x; wS[kk][q*4+1] = wv.y;
            wS[kk][q*4+2] = wv.z; wS[kk][q*4+3] = wv.w;
        }
        __syncthreads();
        for (int hh = 0; hh < 32; ++hh) {
            float4 rv = *(const float4*)&rel[((size_t)r*HID + h0c + hh)*HID + g0 + gi*4];
            #pragma unroll
            for (int ki = 0; ki < 4; ++ki) {
                float ww = wS[kq*4 + ki][hh];
                acc[ki].x += ww*rv.x; acc[ki].y += ww*rv.y;
                acc[ki].z += ww*rv.z; acc[ki].w += ww*rv.w;
            }
        }
    }
    #pragma unroll
    for (int ki = 0; ki < 4; ++ki) {
        int k = kq*4 + ki, g = g0 + gi*4;
        atomicAdd(&prop[(size_t)k*HID + g + 0], acc[ki].x);
        atomicAdd(&prop[(size_t)k*HID + g + 1], acc[ki].y);
        atomicAdd(&prop[(size_t)k*HID + g + 2], acc[ki].z);
        atomicAdd(&prop[(size_t)k*HID + g + 3], acc[ki].w);
    }
}

// -------------------------------------------------------------------------
// K4: sim + CE loss. Inactive entries contribute exactly ln2 each.
// grid (32 k, 16 r), 128 thr (one per j)
// -------------------------------------------------------------------------
__global__ __launch_bounds__(128) void k_simloss(const float* __restrict__ P0,
        const int* __restrict__ rel, const float* __restrict__ v,
        const int* __restrict__ inv, const int* __restrict__ rowflag,
        const int* __restrict__ batchflag, const int* __restrict__ total,
        float* __restrict__ lossAcc)
{
    int k = blockIdx.x, r = blockIdx.y, t = threadIdx.x;
    __shared__ float vS[768];
    __shared__ int ids[128];
    __shared__ int flagS;
    __shared__ float red[128];
    const float* vrow = v + ((size_t)k*NRELD + r)*HID;
    for (int q = 0; q < 6; ++q) vS[t + 128*q] = vrow[t + 128*q];
    ids[t] = rel[((size_t)inv[k]*NRELD + r)*PSZ + t];
    if (t == 0) flagS = total[0] && batchflag[k] && rowflag[k*NRELD + r];
    __syncthreads();
    float term;
    int id = ids[t];
    if (flagS && id != PSZ) {
        const float4* pr = (const float4*)&P0[(size_t)id*HID];
        float z = 0.f;
        for (int q = 0; q < HID/4; ++q) {
            float4 pv = pr[q];
            z += pv.x*vS[q*4+0] + pv.y*vS[q*4+1] + pv.z*vS[q*4+2] + pv.w*vS[q*4+3];
        }
        float s = 1.f/(1.f + expf(-z));
        term = logf(expf(1.f - s) + expf(s)) - s;   // -log_softmax([1-s,s])[1]
    } else {
        term = 0.6931471805599453f;                  // ln 2
    }
    red[t] = term;
    __syncthreads();
    for (int off = 64; off > 0; off >>= 1) {
        if (t < off) red[t] += red[t + off];
        __syncthreads();
    }
    if (t == 0) atomicAdd(lossAcc, red[0]);
}

// -------------------------------------------------------------------------
// K5: proto scatter-update: new = 0.5*old + 0.5*prop/n where n>0
// -------------------------------------------------------------------------
__global__ __launch_bounds__(192) void k_proto(const float* __restrict__ P0,
        const float* __restrict__ prop, const float* __restrict__ nAct,
        const int* __restrict__ rowOwner, float* __restrict__ protoOut)
{
    int p = blockIdx.x, t = threadIdx.x;
    float4 old = *(const float4*)&P0[(size_t)p*HID + t*4];
    float4 o = old;
    int k = rowOwner[p];
    if (k >= 0) {
        float n = nAct[k];
        if (n > 0.f) {
            float4 pr = *(const float4*)&prop[(size_t)k*HID + t*4];
            float invn = 1.f/n;
            o.x = 0.5f*old.x + 0.5f*pr.x*invn;
            o.y = 0.5f*old.y + 0.5f*pr.y*invn;
            o.z = 0.5f*old.z + 0.5f*pr.z*invn;
            o.w = 0.5f*old.w + 0.5f*pr.w*invn;
        }
    }
    *(float4*)&protoOut[(size_t)p*HID + t*4] = o;
}

// -------------------------------------------------------------------------
// K6: logits[b,p] = -||inst[b] - proto[p]||^2
// -------------------------------------------------------------------------
__global__ __launch_bounds__(128) void k_logits(const float* __restrict__ inst,
        const float* __restrict__ protoOut, float* __restrict__ outLogits)
{
    int b = blockIdx.x, t = threadIdx.x;
    __shared__ float iS[768];
    for (int q = 0; q < 6; ++q) iS[t + 128*q] = inst[(size_t)b*HID + t + 128*q];
    __syncthreads();
    const float4* pr = (const float4*)&protoOut[(size_t)t*HID];
    float acc = 0.f;
    for (int q = 0; q < HID/4; ++q) {
        float4 pv = pr[q];
        float dx = iS[q*4+0] - pv.x, dy = iS[q*4+1] - pv.y;
        float dz = iS[q*4+2] - pv.z, dw = iS[q*4+3] - pv.w;
        acc += dx*dx + dy*dy + dz*dz + dw*dw;
    }
    outLogits[b*PSZ + t] = -acc;
}

// -------------------------------------------------------------------------
// K7: finalize loss
// -------------------------------------------------------------------------
__global__ void k_final(const float* __restrict__ lossAcc,
                        const int* __restrict__ total, float* __restrict__ outLoss)
{
    outLoss[0] = total[0] ? lossAcc[0] * (1.f/65536.f) : 0.f;
}

// -------------------------------------------------------------------------
extern "C" void kernel_launch(void* const* d_in, const int* in_sizes, int n_in,
                              void* d_out, int out_size, void* d_ws, size_t ws_size,
                              hipStream_t stream)
{
    const float* inst  = (const float*)d_in[0];   // [32,768]
    const float* rel   = (const float*)d_in[1];   // [16,768,768]
    const int* relIds  = (const int*)d_in[2];     // [32,16,128]
    const int* labels  = (const int*)d_in[3];     // [32]
    const float* P0    = (const float*)d_in[4];   // [128,768]
    float* out = (float*)d_out;
    float* outLogits = out;            // 32*128 = 4096
    float* outLoss   = out + 4096;     // 1
    float* outProto  = out + 4097;     // 128*768 = 98304

    float* f = (float*)d_ws;
    float* v_buf   = f;                 // 393216
    float* w_buf   = f + 393216;        // 393216
    float* prop    = f + 786432;        // 24576
    float* nAct    = f + 811008;        // 32
    float* lossAcc = f + 811040;        // 1 (+31 pad)
    int* ib        = (int*)(f + 811072);
    int* inv       = ib;                // 32
    int* lu        = ib + 32;           // 32
    int* rowflag   = ib + 64;           // 512
    int* batchflag = ib + 576;          // 32
    int* total     = ib + 608;          // 1 (+31 pad)
    int* rowOwner  = ib + 640;          // 128

    k_setup<<<1, 512, 0, stream>>>(labels, relIds, inv, lu, rowflag, batchflag,
                                   total, rowOwner, nAct, lossAcc, prop);
    k_w<<<dim3(32,16), 192, 0, stream>>>(P0, relIds, inv, rowflag, batchflag,
                                         total, w_buf);
    k_v<<<dim3(16,24), 256, 0, stream>>>(rel, P0, lu, v_buf);
    k_prop<<<dim3(16,6,4), 256, 0, stream>>>(rel, w_buf, prop);
    k_simloss<<<dim3(32,16), 128, 0, stream>>>(P0, relIds, v_buf, inv, rowflag,
                                               batchflag, total, lossAcc);
    k_proto<<<128, 192, 0, stream>>>(P0, prop, nAct, rowOwner, outProto);
    k_logits<<<32, 128, 0, stream>>>(inst, outProto, outLogits);
    k_final<<<1, 1, 0, stream>>>(lossAcc, total, outLoss);
}

// Round 2
// 150.679 us; speedup vs baseline: 1.7815x; 1.7815x over previous
//
#include <hip/hip_runtime.h>
#include <hip/hip_bf16.h>
#include <math.h>

#define K_B 32
#define NRELD 16
#define PSZ 128
#define HID 768

using bf16x8 = __attribute__((ext_vector_type(8))) short;
using f32x4  = __attribute__((ext_vector_type(4))) float;

__device__ __forceinline__ unsigned int f2bf(float x) {   // fp32 -> bf16 bits (RNE)
    unsigned int u = __float_as_uint(x);
    return (u + 0x7fffu + ((u >> 16) & 1u)) >> 16;
}
__device__ __forceinline__ float bf2f(unsigned short b) {
    return __uint_as_float(((unsigned int)b) << 16);
}

// -------------------------------------------------------------------------
// K0: ranks, unique labels, masks, active counts, owner map, zero prop/loss
// -------------------------------------------------------------------------
__global__ __launch_bounds__(512) void k_setup(const int* __restrict__ labels,
        const int* __restrict__ rel, int* __restrict__ inv, int* __restrict__ lu,
        int* __restrict__ rowflag, int* __restrict__ batchflag,
        int* __restrict__ total, int* __restrict__ rowOwner,
        float* __restrict__ nAct, float* __restrict__ lossAcc,
        float* __restrict__ prop)
{
    __shared__ int lab[32], rankS[32], luS[32], ownS[128];
    __shared__ int rowflagS[512], cntS[512], bfS[32], totS;
    int t = threadIdx.x;
    if (t < 32) lab[t] = labels[t];
    __syncthreads();
    if (t < 32) {
        int r = 0;
        for (int j = 0; j < 32; ++j) r += (lab[j] < lab[t]);
        rankS[t] = r; inv[t] = r;
    }
    if (t < 128) ownS[t] = -1;
    __syncthreads();
    if (t < 32) luS[rankS[t]] = lab[t];
    __syncthreads();
    if (t < 32) { lu[t] = luS[t]; ownS[luS[t]] = t; }
    __syncthreads();
    if (t < 128) rowOwner[t] = ownS[t];
    {
        int k = t >> 4, i = t & 15;
        const int* rp = rel + ((size_t)rankS[k] * NRELD + i) * PSZ;
        int s = 0, c = 0;
        for (int j = 0; j < PSZ; ++j) { int v_ = rp[j]; s += v_; c += (v_ != PSZ); }
        rowflagS[t] = (s > 0); cntS[t] = c;
        rowflag[t] = (s > 0);
    }
    __syncthreads();
    if (t < 32) {
        int b = 0;
        for (int i = 0; i < 16; ++i) b |= rowflagS[t*16 + i];
        bfS[t] = b; batchflag[t] = b;
    }
    __syncthreads();
    if (t == 0) {
        int tt = 0;
        for (int k = 0; k < 32; ++k) tt |= bfS[k];
        totS = tt; total[0] = tt; lossAcc[0] = 0.f;
    }
    __syncthreads();
    if (t < 32) {
        float n = 0.f;
        if (totS && bfS[t])
            for (int i = 0; i < 16; ++i)
                if (rowflagS[t*16 + i]) n += (float)cntS[t*16 + i];
        nAct[t] = n;
    }
    for (int idx = t; idx < K_B*HID; idx += 512) prop[idx] = 0.f;
}

// -------------------------------------------------------------------------
// K1 (k_prep): S histogram (flag-gated) + P0/P0T/pt bf16 conversions
// grid 512 (kr), 192 thr; blocks 0..127 also convert P0 row p=bid
// -------------------------------------------------------------------------
__global__ __launch_bounds__(192) void k_prep(
        const int* __restrict__ relIds, const int* __restrict__ inv,
        const int* __restrict__ rowflag, const int* __restrict__ batchflag,
        const int* __restrict__ total, const int* __restrict__ rowOwner,
        const float* __restrict__ P0,
        unsigned short* __restrict__ S_bf, unsigned short* __restrict__ P0_bf,
        unsigned short* __restrict__ P0T_bf, unsigned short* __restrict__ pt_bf)
{
    int bid = blockIdx.x, t = threadIdx.x;
    int k = bid >> 4, r = bid & 15;
    __shared__ int hist[128];
    if (t < 128) hist[t] = 0;
    __syncthreads();
    int flag = total[0] && batchflag[k] && rowflag[k*NRELD + r];
    if (flag && t < 128) {
        int id = relIds[((size_t)inv[k]*NRELD + r)*PSZ + t];
        if (id != PSZ) atomicAdd(&hist[id], 1);
    }
    __syncthreads();
    if (t < 128) S_bf[(size_t)bid*128 + t] = (unsigned short)f2bf((float)hist[t]);
    if (bid < 128) {
        int p = bid;
        float4 v4 = *(const float4*)&P0[(size_t)p*HID + t*4];
        unsigned int b0 = f2bf(v4.x), b1 = f2bf(v4.y), b2 = f2bf(v4.z), b3 = f2bf(v4.w);
        uint2 d; d.x = b0 | (b1 << 16); d.y = b2 | (b3 << 16);
        *(uint2*)&P0_bf[(size_t)p*HID + t*4] = d;
        P0T_bf[(size_t)(t*4+0)*128 + p] = (unsigned short)b0;
        P0T_bf[(size_t)(t*4+1)*128 + p] = (unsigned short)b1;
        P0T_bf[(size_t)(t*4+2)*128 + p] = (unsigned short)b2;
        P0T_bf[(size_t)(t*4+3)*128 + p] = (unsigned short)b3;
        int kk = rowOwner[p];
        if (kk >= 0) *(uint2*)&pt_bf[(size_t)kk*HID + t*4] = d;
    }
}

// -------------------------------------------------------------------------
// K2: v[h,k] per r = Rel_r[768x768] x pt^T  (MFMA bf16, fp32 staging)
// grid (16 r, 12 h-slabs of 64), 256 thr. Output v_bf[(k*16+r)*768+h].
// -------------------------------------------------------------------------
__global__ __launch_bounds__(256) void k_v_mfma(
        const float* __restrict__ rel, const unsigned short* __restrict__ pt_bf,
        unsigned short* __restrict__ v_bf)
{
    int r = blockIdx.x, hs = blockIdx.y, t = threadIdx.x;
    int wave = t >> 6, lane = t & 63;
    __shared__ unsigned short ptS[32*768];   // [k][g], chunk c^=(k&7)
    __shared__ unsigned short AS[64*128];    // [h][g-tile 128], chunk c^=(h&7)

    for (int i = t; i < 3072; i += 256) {    // stage pt (48 KB)
        int k = i / 96, c = i % 96;
        uint4 d = *(const uint4*)&pt_bf[(size_t)k*HID + c*8];
        *(uint4*)&ptS[k*768 + (c ^ (k & 7))*8] = d;
    }

    const int gq = (t & 31) * 4;             // g within tile (0..124)
    const int hr = t >> 5;                   // 0..7
    const size_t relbase = ((size_t)r*HID + hs*64) * HID;

    float4 buf[8];
    #pragma unroll
    for (int rr = 0; rr < 8; ++rr)
        buf[rr] = *(const float4*)&rel[relbase + (size_t)(hr + rr*8)*HID + gq];

    f32x4 acc[2] = {{0.f,0.f,0.f,0.f},{0.f,0.f,0.f,0.f}};
    const int arow = wave*16 + (lane & 15);  // h local (0..63)

    for (int gt = 0; gt < 6; ++gt) {
        int g0 = gt * 128;
        __syncthreads();
        #pragma unroll
        for (int rr = 0; rr < 8; ++rr) {     // cvt + LDS write
            int h_l = hr + rr*8;
            float4 v4 = buf[rr];
            int cs = (gq >> 3) ^ (h_l & 7);
            uint2 d; d.x = f2bf(v4.x) | (f2bf(v4.y) << 16);
            d.y = f2bf(v4.z) | (f2bf(v4.w) << 16);
            *(uint2*)&AS[h_l*128 + cs*8 + (gq & 4)] = d;
        }
        __syncthreads();
        if (gt < 5) {
            int gn = g0 + 128;
            #pragma unroll
            for (int rr = 0; rr < 8; ++rr)
                buf[rr] = *(const float4*)&rel[relbase + (size_t)(hr + rr*8)*HID + gn + gq];
        }
        #pragma unroll
        for (int kk = 0; kk < 4; ++kk) {
            int cA = (kk*4 + (lane >> 4)) ^ (arow & 7);
            bf16x8 a = *(const bf16x8*)&AS[arow*128 + cA*8];
            #pragma unroll
            for (int nf = 0; nf < 2; ++nf) {
                int k = nf*16 + (lane & 15);
                int cB = (gt*16 + kk*4 + (lane >> 4)) ^ (k & 7);
                bf16x8 b = *(const bf16x8*)&ptS[k*768 + cB*8];
                acc[nf] = __builtin_amdgcn_mfma_f32_16x16x32_bf16(a, b, acc[nf], 0, 0, 0);
            }
        }
    }
    int h_out = hs*64 + wave*16 + (lane >> 4) * 4;   // D: row=h, col=k
    #pragma unroll
    for (int nf = 0; nf < 2; ++nf) {
        int k = nf*16 + (lane & 15);
        uint2 d; d.x = f2bf(acc[nf][0]) | (f2bf(acc[nf][1]) << 16);
        d.y = f2bf(acc[nf][2]) | (f2bf(acc[nf][3]) << 16);
        *(uint2*)&v_bf[((size_t)k*NRELD + r)*HID + h_out] = d;
    }
}

// -------------------------------------------------------------------------
// K3: w[(kr),h] = S[(kr),p] x P0T[h,p]  (M=512,N=768,K=128) MFMA
// grid (8, 12), 256 thr
// -------------------------------------------------------------------------
__global__ __launch_bounds__(256) void k_w_mfma(
        const unsigned short* __restrict__ S_bf, const unsigned short* __restrict__ P0T_bf,
        unsigned short* __restrict__ w_bf)
{
    int ms = blockIdx.x, ns = blockIdx.y, t = threadIdx.x;
    int wave = t >> 6, lane = t & 63;
    __shared__ unsigned short AS[64*128], BS2[64*128];
    for (int i = t; i < 1024; i += 256) {
        int row = i >> 4, c = i & 15;
        *(uint4*)&AS[row*128 + (c ^ (row & 7))*8] =
            *(const uint4*)&S_bf[(size_t)(ms*64 + row)*128 + c*8];
        *(uint4*)&BS2[row*128 + (c ^ (row & 7))*8] =
            *(const uint4*)&P0T_bf[(size_t)(ns*64 + row)*128 + c*8];
    }
    __syncthreads();
    f32x4 acc[4] = {{0.f,0.f,0.f,0.f},{0.f,0.f,0.f,0.f},{0.f,0.f,0.f,0.f},{0.f,0.f,0.f,0.f}};
    int arow = wave*16 + (lane & 15);
    #pragma unroll
    for (int kk = 0; kk < 4; ++kk) {
        int cA = (kk*4 + (lane >> 4)) ^ (arow & 7);
        bf16x8 a = *(const bf16x8*)&AS[arow*128 + cA*8];
        #pragma unroll
        for (int nf = 0; nf < 4; ++nf) {
            int brow = nf*16 + (lane & 15);
            int cB = (kk*4 + (lane >> 4)) ^ (brow & 7);
            bf16x8 b = *(const bf16x8*)&BS2[brow*128 + cB*8];
            acc[nf] = __builtin_amdgcn_mfma_f32_16x16x32_bf16(a, b, acc[nf], 0, 0, 0);
        }
    }
    int kr0 = ms*64 + wave*16 + (lane >> 4) * 4;
    #pragma unroll
    for (int nf = 0; nf < 4; ++nf) {
        int h = ns*64 + nf*16 + (lane & 15);
        #pragma unroll
        for (int j = 0; j < 4; ++j)
            w_bf[(size_t)(kr0 + j)*HID + h] = (unsigned short)f2bf(acc[nf][j]);
    }
}

// -------------------------------------------------------------------------
// K4: prop[k,g] += W_r[k,h] x Rel_r[h,g]  (contraction h -> LDS transpose)
// grid (16 r, 12 g-slabs of 64), 256 thr, atomic accumulate over r
// -------------------------------------------------------------------------
__global__ __launch_bounds__(256) void k_prop_mfma(
        const float* __restrict__ rel, const unsigned short* __restrict__ w_bf,
        float* __restrict__ prop)
{
    int r = blockIdx.x, gs = blockIdx.y, t = threadIdx.x;
    int wave = t >> 6, lane = t & 63;
    __shared__ unsigned short WS[32*768];   // [k][h], chunk c^=(k&7)
    __shared__ unsigned short BS[64*128];   // [g_l][h-tile 128], chunk c^=((g>>2)&7)

    for (int i = t; i < 3072; i += 256) {   // stage W_r (48 KB)
        int k = i / 96, c = i % 96;
        uint4 d = *(const uint4*)&w_bf[((size_t)k*NRELD + r)*HID + c*8];
        *(uint4*)&WS[k*768 + (c ^ (k & 7))*8] = d;
    }

    const int gqq = t & 15;                 // g-quad
    const int h4  = t >> 4;                 // 0..15
    const size_t relb = (size_t)r*HID*HID + (size_t)gs*64;

    float4 buf[8];
    #pragma unroll
    for (int sup = 0; sup < 2; ++sup)
        #pragma unroll
        for (int rr = 0; rr < 4; ++rr)
            buf[sup*4+rr] = *(const float4*)&rel[relb + (size_t)(sup*64 + h4*4 + rr)*HID + gqq*4];

    f32x4 acc[2] = {{0.f,0.f,0.f,0.f},{0.f,0.f,0.f,0.f}};

    for (int ht = 0; ht < 6; ++ht) {
        int ht0 = ht * 128;
        __syncthreads();
        #pragma unroll
        for (int sup = 0; sup < 2; ++sup) {
            #pragma unroll
            for (int i = 0; i < 4; ++i) {   // transpose-pack: BS[g][h..h+3]
                int g_l = gqq*4 + i;
                int hloc = sup*64 + h4*4;
                unsigned int p0 = f2bf(((const float*)&buf[sup*4+0])[i]);
                unsigned int p1 = f2bf(((const float*)&buf[sup*4+1])[i]);
                unsigned int p2 = f2bf(((const float*)&buf[sup*4+2])[i]);
                unsigned int p3 = f2bf(((const float*)&buf[sup*4+3])[i]);
                int cs = (hloc >> 3) ^ ((g_l >> 2) & 7);
                uint2 d; d.x = p0 | (p1 << 16); d.y = p2 | (p3 << 16);
                *(uint2*)&BS[g_l*128 + cs*8 + (hloc & 4)] = d;
            }
        }
        __syncthreads();
        if (ht < 5) {
            int hn = ht0 + 128;
            #pragma unroll
            for (int sup = 0; sup < 2; ++sup)
                #pragma unroll
                for (int rr = 0; rr < 4; ++rr)
                    buf[sup*4+rr] = *(const float4*)&rel[relb + (size_t)(hn + sup*64 + h4*4 + rr)*HID + gqq*4];
        }
        int g_l = wave*16 + (lane & 15);
        #pragma unroll
        for (int kk = 0; kk < 4; ++kk) {
            int cB = (kk*4 + (lane >> 4)) ^ ((g_l >> 2) & 7);
            bf16x8 b = *(const bf16x8*)&BS[g_l*128 + cB*8];
            #pragma unroll
            for (int mf = 0; mf < 2; ++mf) {
                int arow = mf*16 + (lane & 15);
                int cA = (ht*16 + kk*4 + (lane >> 4)) ^ (arow & 7);
                bf16x8 a = *(const bf16x8*)&WS[arow*768 + cA*8];
                acc[mf] = __builtin_amdgcn_mfma_f32_16x16x32_bf16(a, b, acc[mf], 0, 0, 0);
            }
        }
    }
    int gcol = gs*64 + wave*16 + (lane & 15);
    #pragma unroll
    for (int mf = 0; mf < 2; ++mf) {
        int k0 = mf*16 + (lane >> 4) * 4;
        #pragma unroll
        for (int j = 0; j < 4; ++j)
            atomicAdd(&prop[(size_t)(k0 + j)*HID + gcol], acc[mf][j]);
    }
}

// -------------------------------------------------------------------------
// K5: zz[(kr),p] = v[(kr),h] x P0[p,h]  + fused CE-loss accumulation
// grid 32 (kr-slabs of 16), 256 thr
// -------------------------------------------------------------------------
__global__ __launch_bounds__(256) void k_zzloss(
        const unsigned short* __restrict__ v_bf, const unsigned short* __restrict__ P0_bf,
        const unsigned short* __restrict__ S_bf, float* __restrict__ lossAcc)
{
    int ms = blockIdx.x, t = threadIdx.x;
    int wave = t >> 6, lane = t & 63;
    __shared__ unsigned short AS[16*128], BS2[128*128];
    __shared__ float red[256];
    f32x4 acc[2] = {{0.f,0.f,0.f,0.f},{0.f,0.f,0.f,0.f}};

    for (int ht = 0; ht < 6; ++ht) {
        int h0 = ht * 128;
        __syncthreads();
        {
            int row = t >> 4, c = t & 15;
            *(uint4*)&AS[row*128 + (c ^ (row & 7))*8] =
                *(const uint4*)&v_bf[(size_t)(ms*16 + row)*HID + h0 + c*8];
            #pragma unroll
            for (int q = 0; q < 8; ++q) {
                int j2 = t + q*256;
                int prow = j2 >> 4, c2 = j2 & 15;
                *(uint4*)&BS2[prow*128 + (c2 ^ (prow & 7))*8] =
                    *(const uint4*)&P0_bf[(size_t)prow*HID + h0 + c2*8];
            }
        }
        __syncthreads();
        int arow = lane & 15;
        #pragma unroll
        for (int kk = 0; kk < 4; ++kk) {
            int cA = (kk*4 + (lane >> 4)) ^ (arow & 7);
            bf16x8 a = *(const bf16x8*)&AS[arow*128 + cA*8];
            #pragma unroll
            for (int nf = 0; nf < 2; ++nf) {
                int brow = wave*32 + nf*16 + (lane & 15);
                int cB = (kk*4 + (lane >> 4)) ^ (brow & 7);
                bf16x8 b = *(const bf16x8*)&BS2[brow*128 + cB*8];
                acc[nf] = __builtin_amdgcn_mfma_f32_16x16x32_bf16(a, b, acc[nf], 0, 0, 0);
            }
        }
    }
    float term = 0.f;
    #pragma unroll
    for (int nf = 0; nf < 2; ++nf) {
        int p = wave*32 + nf*16 + (lane & 15);
        int kr0 = ms*16 + (lane >> 4) * 4;
        #pragma unroll
        for (int j = 0; j < 4; ++j) {
            float S = bf2f(S_bf[(size_t)(kr0 + j)*128 + p]);
            if (S != 0.f) {
                float z = acc[nf][j];
                float s = 1.f / (1.f + expf(-z));
                term += S * (logf(expf(1.f - s) + expf(s)) - s);
            }
        }
    }
    red[t] = term;
    __syncthreads();
    for (int off = 128; off; off >>= 1) {
        if (t < off) red[t] += red[t + off];
        __syncthreads();
    }
    if (t == 0) atomicAdd(lossAcc, red[0]);
}

// -------------------------------------------------------------------------
// K6: proto scatter-update
// -------------------------------------------------------------------------
__global__ __launch_bounds__(192) void k_proto(const float* __restrict__ P0,
        const float* __restrict__ prop, const float* __restrict__ nAct,
        const int* __restrict__ rowOwner, float* __restrict__ protoOut)
{
    int p = blockIdx.x, t = threadIdx.x;
    float4 old = *(const float4*)&P0[(size_t)p*HID + t*4];
    float4 o = old;
    int k = rowOwner[p];
    if (k >= 0) {
        float n = nAct[k];
        if (n > 0.f) {
            float4 pr = *(const float4*)&prop[(size_t)k*HID + t*4];
            float invn = 1.f/n;
            o.x = 0.5f*old.x + 0.5f*pr.x*invn;
            o.y = 0.5f*old.y + 0.5f*pr.y*invn;
            o.z = 0.5f*old.z + 0.5f*pr.z*invn;
            o.w = 0.5f*old.w + 0.5f*pr.w*invn;
        }
    }
    *(float4*)&protoOut[(size_t)p*HID + t*4] = o;
}

// -------------------------------------------------------------------------
// K7: logits[b,p] = -||inst[b] - proto[p]||^2   (+ loss finalize in blk 0)
// -------------------------------------------------------------------------
__global__ __launch_bounds__(128) void k_logits(const float* __restrict__ inst,
        const float* __restrict__ protoOut, const float* __restrict__ lossAcc,
        const int* __restrict__ total, const float* __restrict__ nAct,
        float* __restrict__ outLogits, float* __restrict__ outLoss)
{
    int b = blockIdx.x, t = threadIdx.x;
    __shared__ float iS[768];
    for (int q = 0; q < 6; ++q) iS[t + 128*q] = inst[(size_t)b*HID + t + 128*q];
    __syncthreads();
    const float4* pr = (const float4*)&protoOut[(size_t)t*HID];
    float acc = 0.f;
    for (int q = 0; q < HID/4; ++q) {
        float4 pv = pr[q];
        float dx = iS[q*4+0] - pv.x, dy = iS[q*4+1] - pv.y;
        float dz = iS[q*4+2] - pv.z, dw = iS[q*4+3] - pv.w;
        acc += dx*dx + dy*dy + dz*dz + dw*dw;
    }
    outLogits[b*PSZ + t] = -acc;
    if (b == 0 && t == 0) {
        float na = 0.f;
        for (int k = 0; k < 32; ++k) na += nAct[k];
        outLoss[0] = total[0]
            ? (lossAcc[0] + (65536.f - na) * 0.6931471805599453f) * (1.f/65536.f)
            : 0.f;
    }
}

// -------------------------------------------------------------------------
extern "C" void kernel_launch(void* const* d_in, const int* in_sizes, int n_in,
                              void* d_out, int out_size, void* d_ws, size_t ws_size,
                              hipStream_t stream)
{
    const float* inst  = (const float*)d_in[0];   // [32,768]
    const float* rel   = (const float*)d_in[1];   // [16,768,768]
    const int* relIds  = (const int*)d_in[2];     // [32,16,128]
    const int* labels  = (const int*)d_in[3];     // [32]
    const float* P0    = (const float*)d_in[4];   // [128,768]
    float* out = (float*)d_out;
    float* outLogits = out;            // 4096
    float* outLoss   = out + 4096;     // 1
    float* outProto  = out + 4097;     // 98304

    char* ws = (char*)d_ws;
    unsigned short* v_bf    = (unsigned short*)(ws + 0);        // 786432 B
    unsigned short* w_bf    = (unsigned short*)(ws + 786432);   // 786432 B
    unsigned short* S_bf    = (unsigned short*)(ws + 1572864);  // 131072 B
    unsigned short* P0_bf   = (unsigned short*)(ws + 1703936);  // 196608 B
    unsigned short* P0T_bf  = (unsigned short*)(ws + 1900544);  // 196608 B
    unsigned short* pt_bf   = (unsigned short*)(ws + 2097152);  // 49152 B
    float* prop    = (float*)(ws + 2146304);                    // 98304 B
    float* nAct    = (float*)(ws + 2244608);                    // 128 B
    float* lossAcc = (float*)(ws + 2244736);                    // 128 B
    int*   inv     = (int*)(ws + 2244864);
    int*   lu      = (int*)(ws + 2244992);
    int*   rowflag = (int*)(ws + 2245120);                      // 2048 B
    int*   batchflag = (int*)(ws + 2247168);
    int*   total   = (int*)(ws + 2247296);
    int*   rowOwner= (int*)(ws + 2247424);                      // 512 B

    k_setup<<<1, 512, 0, stream>>>(labels, relIds, inv, lu, rowflag, batchflag,
                                   total, rowOwner, nAct, lossAcc, prop);
    k_prep<<<512, 192, 0, stream>>>(relIds, inv, rowflag, batchflag, total,
                                    rowOwner, P0, S_bf, P0_bf, P0T_bf, pt_bf);
    k_v_mfma<<<dim3(16,12), 256, 0, stream>>>(rel, pt_bf, v_bf);
    k_w_mfma<<<dim3(8,12), 256, 0, stream>>>(S_bf, P0T_bf, w_bf);
    k_prop_mfma<<<dim3(16,12), 256, 0, stream>>>(rel, w_bf, prop);
    k_zzloss<<<32, 256, 0, stream>>>(v_bf, P0_bf, S_bf, lossAcc);
    k_proto<<<128, 192, 0, stream>>>(P0, prop, nAct, rowOwner, outProto);
    k_logits<<<32, 128, 0, stream>>>(inst, outProto, lossAcc, total, nAct,
                                     outLogits, outLoss);
}

// Round 3
// 136.494 us; speedup vs baseline: 1.9666x; 1.1039x over previous
//
#include <hip/hip_runtime.h>
#include <hip/hip_bf16.h>
#include <math.h>

#define K_B 32
#define NRELD 16
#define PSZ 128
#define HID 768

using bf16x8 = __attribute__((ext_vector_type(8))) short;
using f32x4  = __attribute__((ext_vector_type(4))) float;

__device__ __forceinline__ unsigned int f2bf(float x) {   // fp32 -> bf16 bits (RNE)
    unsigned int u = __float_as_uint(x);
    return (u + 0x7fffu + ((u >> 16) & 1u)) >> 16;
}
__device__ __forceinline__ float bf2f(unsigned short b) {
    return __uint_as_float(((unsigned int)b) << 16);
}

// -------------------------------------------------------------------------
// K0: per-(k,r) gated histogram S, rowflag/cntRow; blocks<128 convert P0.
// Gating note: batchflag/total are implied by rowflag (sums of non-negative
// ints), so the mask is (id != 128) && rowflag — fully row-local.
// grid 512 (k*16+r), 192 thr
// -------------------------------------------------------------------------
__global__ __launch_bounds__(192) void k_prep(
        const int* __restrict__ labels, const int* __restrict__ relIds,
        const float* __restrict__ P0,
        unsigned short* __restrict__ S_bf, unsigned short* __restrict__ P0_bf,
        unsigned short* __restrict__ P0T_bf, unsigned short* __restrict__ pt_bf,
        int* __restrict__ rowflag, int* __restrict__ cntRow,
        int* __restrict__ rowOwner_g)
{
    int bid = blockIdx.x, t = threadIdx.x;
    int k = bid >> 4, r = bid & 15;
    __shared__ int lab[32], rankS[32], luS[32], ownS[128];
    __shared__ int hist[128], redS[128];
    if (t < 32) lab[t] = labels[t];
    if (t < 128) { hist[t] = 0; ownS[t] = -1; }
    __syncthreads();
    if (t < 32) { int rk = 0; for (int j = 0; j < 32; ++j) rk += (lab[j] < lab[t]); rankS[t] = rk; }
    __syncthreads();
    if (t < 32) luS[rankS[t]] = lab[t];
    __syncthreads();
    if (t < 32) ownS[luS[t]] = t;
    __syncthreads();

    int id = 0, isv = 0;
    if (t < 128) {
        id = relIds[((size_t)rankS[k]*NRELD + r)*PSZ + t];
        isv = (id != PSZ);
        if (isv) atomicAdd(&hist[id], 1);
        redS[t] = id + (isv << 20);          // rowsum (<2^20) | cnt<<20
    }
    __syncthreads();
    for (int off = 64; off; off >>= 1) {
        if (t < off) redS[t] += redS[t + off];
        __syncthreads();
    }
    int rowsum = redS[0] & 0xFFFFF;
    int cnt    = redS[0] >> 20;
    int rf     = (rowsum > 0);
    if (t < 128)
        S_bf[(size_t)bid*128 + t] = (unsigned short)f2bf(rf ? (float)hist[t] : 0.f);
    if (t == 0) { rowflag[bid] = rf; cntRow[bid] = cnt; }
    if (bid == 0 && t < 128) rowOwner_g[t] = ownS[t];

    if (bid < 128) {                          // P0 conversions (row p = bid)
        int p = bid;
        float4 v4 = *(const float4*)&P0[(size_t)p*HID + t*4];
        unsigned int b0 = f2bf(v4.x), b1 = f2bf(v4.y), b2 = f2bf(v4.z), b3 = f2bf(v4.w);
        uint2 d; d.x = b0 | (b1 << 16); d.y = b2 | (b3 << 16);
        *(uint2*)&P0_bf[(size_t)p*HID + t*4] = d;
        P0T_bf[(size_t)(t*4+0)*128 + p] = (unsigned short)b0;
        P0T_bf[(size_t)(t*4+1)*128 + p] = (unsigned short)b1;
        P0T_bf[(size_t)(t*4+2)*128 + p] = (unsigned short)b2;
        P0T_bf[(size_t)(t*4+3)*128 + p] = (unsigned short)b3;
        int kk = ownS[p];
        if (kk >= 0) *(uint2*)&pt_bf[(size_t)kk*HID + t*4] = d;
    }
}

// -------------------------------------------------------------------------
// K1: fused  v (blocks 0..191)  +  w (blocks 192..287, also zero prop/loss)
// -------------------------------------------------------------------------
__global__ __launch_bounds__(256) void k_vw(
        const float* __restrict__ rel, const unsigned short* __restrict__ pt_bf,
        const unsigned short* __restrict__ S_bf, const unsigned short* __restrict__ P0T_bf,
        unsigned short* __restrict__ v_bf, unsigned short* __restrict__ w_bf,
        float* __restrict__ prop, float* __restrict__ lossAcc)
{
    __shared__ unsigned short sh[32*768 + 64*128];
    int bid = blockIdx.x, t = threadIdx.x;
    int wave = t >> 6, lane = t & 63;

    if (bid < 192) {
        // ---- v role: v[h,k] per r = Rel_r x pt^T ----
        int r = bid & 15, hs = bid >> 4;
        unsigned short* ptS = sh;            // [k][g], chunk c^=(k&7)
        unsigned short* AS  = sh + 32*768;   // [h][g-tile 128], chunk c^=(h&7)

        for (int i = t; i < 3072; i += 256) {
            int k = i / 96, c = i % 96;
            uint4 d = *(const uint4*)&pt_bf[(size_t)k*HID + c*8];
            *(uint4*)&ptS[k*768 + (c ^ (k & 7))*8] = d;
        }
        const int gq = (t & 31) * 4;
        const int hr = t >> 5;
        const size_t relbase = ((size_t)r*HID + hs*64) * HID;

        float4 buf[8];
        #pragma unroll
        for (int rr = 0; rr < 8; ++rr)
            buf[rr] = *(const float4*)&rel[relbase + (size_t)(hr + rr*8)*HID + gq];

        f32x4 acc[2] = {{0.f,0.f,0.f,0.f},{0.f,0.f,0.f,0.f}};
        const int arow = wave*16 + (lane & 15);

        for (int gt = 0; gt < 6; ++gt) {
            __syncthreads();
            #pragma unroll
            for (int rr = 0; rr < 8; ++rr) {
                int h_l = hr + rr*8;
                float4 v4 = buf[rr];
                int cs = (gq >> 3) ^ (h_l & 7);
                uint2 d; d.x = f2bf(v4.x) | (f2bf(v4.y) << 16);
                d.y = f2bf(v4.z) | (f2bf(v4.w) << 16);
                *(uint2*)&AS[h_l*128 + cs*8 + (gq & 4)] = d;
            }
            __syncthreads();
            if (gt < 5) {
                int gn = gt*128 + 128;
                #pragma unroll
                for (int rr = 0; rr < 8; ++rr)
                    buf[rr] = *(const float4*)&rel[relbase + (size_t)(hr + rr*8)*HID + gn + gq];
            }
            #pragma unroll
            for (int kk = 0; kk < 4; ++kk) {
                int cA = (kk*4 + (lane >> 4)) ^ (arow & 7);
                bf16x8 a = *(const bf16x8*)&AS[arow*128 + cA*8];
                #pragma unroll
                for (int nf = 0; nf < 2; ++nf) {
                    int k = nf*16 + (lane & 15);
                    int cB = (gt*16 + kk*4 + (lane >> 4)) ^ (k & 7);
                    bf16x8 b = *(const bf16x8*)&ptS[k*768 + cB*8];
                    acc[nf] = __builtin_amdgcn_mfma_f32_16x16x32_bf16(a, b, acc[nf], 0, 0, 0);
                }
            }
        }
        int h_out = hs*64 + wave*16 + (lane >> 4) * 4;
        #pragma unroll
        for (int nf = 0; nf < 2; ++nf) {
            int k = nf*16 + (lane & 15);
            uint2 d; d.x = f2bf(acc[nf][0]) | (f2bf(acc[nf][1]) << 16);
            d.y = f2bf(acc[nf][2]) | (f2bf(acc[nf][3]) << 16);
            *(uint2*)&v_bf[((size_t)k*NRELD + r)*HID + h_out] = d;
        }
    } else {
        // ---- w role: w[(kr),h] = S x P0T ----
        int idx = bid - 192;                 // 0..95
        int ms = idx / 12, ns = idx % 12;
        unsigned short* AS2 = sh;
        unsigned short* BS2 = sh + 64*128;
        // zero prop (96 blocks x 256 floats) + lossAcc
        if (t < 64) *(float4*)&prop[idx*256 + t*4] = float4{0.f,0.f,0.f,0.f};
        if (idx == 0 && t == 0) lossAcc[0] = 0.f;

        for (int i = t; i < 1024; i += 256) {
            int row = i >> 4, c = i & 15;
            *(uint4*)&AS2[row*128 + (c ^ (row & 7))*8] =
                *(const uint4*)&S_bf[(size_t)(ms*64 + row)*128 + c*8];
            *(uint4*)&BS2[row*128 + (c ^ (row & 7))*8] =
                *(const uint4*)&P0T_bf[(size_t)(ns*64 + row)*128 + c*8];
        }
        __syncthreads();
        f32x4 acc[4] = {{0.f,0.f,0.f,0.f},{0.f,0.f,0.f,0.f},{0.f,0.f,0.f,0.f},{0.f,0.f,0.f,0.f}};
        int arow = wave*16 + (lane & 15);
        #pragma unroll
        for (int kk = 0; kk < 4; ++kk) {
            int cA = (kk*4 + (lane >> 4)) ^ (arow & 7);
            bf16x8 a = *(const bf16x8*)&AS2[arow*128 + cA*8];
            #pragma unroll
            for (int nf = 0; nf < 4; ++nf) {
                int brow = nf*16 + (lane & 15);
                int cB = (kk*4 + (lane >> 4)) ^ (brow & 7);
                bf16x8 b = *(const bf16x8*)&BS2[brow*128 + cB*8];
                acc[nf] = __builtin_amdgcn_mfma_f32_16x16x32_bf16(a, b, acc[nf], 0, 0, 0);
            }
        }
        int kr0 = ms*64 + wave*16 + (lane >> 4) * 4;
        #pragma unroll
        for (int nf = 0; nf < 4; ++nf) {
            int h = ns*64 + nf*16 + (lane & 15);
            #pragma unroll
            for (int j = 0; j < 4; ++j)
                w_bf[(size_t)(kr0 + j)*HID + h] = (unsigned short)f2bf(acc[nf][j]);
        }
    }
}

// -------------------------------------------------------------------------
// K2: prop[k,g] += W_r[k,h] x Rel_r[h,g]   grid (16 r, 12 g-slabs), 256 thr
// -------------------------------------------------------------------------
__global__ __launch_bounds__(256) void k_prop_mfma(
        const float* __restrict__ rel, const unsigned short* __restrict__ w_bf,
        float* __restrict__ prop)
{
    int r = blockIdx.x, gs = blockIdx.y, t = threadIdx.x;
    int wave = t >> 6, lane = t & 63;
    __shared__ unsigned short WS[32*768];
    __shared__ unsigned short BS[64*128];

    for (int i = t; i < 3072; i += 256) {
        int k = i / 96, c = i % 96;
        uint4 d = *(const uint4*)&w_bf[((size_t)k*NRELD + r)*HID + c*8];
        *(uint4*)&WS[k*768 + (c ^ (k & 7))*8] = d;
    }
    const int gqq = t & 15;
    const int h4  = t >> 4;
    const size_t relb = (size_t)r*HID*HID + (size_t)gs*64;

    float4 buf[8];
    #pragma unroll
    for (int sup = 0; sup < 2; ++sup)
        #pragma unroll
        for (int rr = 0; rr < 4; ++rr)
            buf[sup*4+rr] = *(const float4*)&rel[relb + (size_t)(sup*64 + h4*4 + rr)*HID + gqq*4];

    f32x4 acc[2] = {{0.f,0.f,0.f,0.f},{0.f,0.f,0.f,0.f}};

    for (int ht = 0; ht < 6; ++ht) {
        __syncthreads();
        #pragma unroll
        for (int sup = 0; sup < 2; ++sup) {
            #pragma unroll
            for (int i = 0; i < 4; ++i) {
                int g_l = gqq*4 + i;
                int hloc = sup*64 + h4*4;
                unsigned int p0 = f2bf(((const float*)&buf[sup*4+0])[i]);
                unsigned int p1 = f2bf(((const float*)&buf[sup*4+1])[i]);
                unsigned int p2 = f2bf(((const float*)&buf[sup*4+2])[i]);
                unsigned int p3 = f2bf(((const float*)&buf[sup*4+3])[i]);
                int cs = (hloc >> 3) ^ ((g_l >> 2) & 7);
                uint2 d; d.x = p0 | (p1 << 16); d.y = p2 | (p3 << 16);
                *(uint2*)&BS[g_l*128 + cs*8 + (hloc & 4)] = d;
            }
        }
        __syncthreads();
        if (ht < 5) {
            int hn = ht*128 + 128;
            #pragma unroll
            for (int sup = 0; sup < 2; ++sup)
                #pragma unroll
                for (int rr = 0; rr < 4; ++rr)
                    buf[sup*4+rr] = *(const float4*)&rel[relb + (size_t)(hn + sup*64 + h4*4 + rr)*HID + gqq*4];
        }
        int g_l = wave*16 + (lane & 15);
        #pragma unroll
        for (int kk = 0; kk < 4; ++kk) {
            int cB = (kk*4 + (lane >> 4)) ^ ((g_l >> 2) & 7);
            bf16x8 b = *(const bf16x8*)&BS[g_l*128 + cB*8];
            #pragma unroll
            for (int mf = 0; mf < 2; ++mf) {
                int arow = mf*16 + (lane & 15);
                int cA = (ht*16 + kk*4 + (lane >> 4)) ^ (arow & 7);
                bf16x8 a = *(const bf16x8*)&WS[arow*768 + cA*8];
                acc[mf] = __builtin_amdgcn_mfma_f32_16x16x32_bf16(a, b, acc[mf], 0, 0, 0);
            }
        }
    }
    int gcol = gs*64 + wave*16 + (lane & 15);
    #pragma unroll
    for (int mf = 0; mf < 2; ++mf) {
        int k0 = mf*16 + (lane >> 4) * 4;
        #pragma unroll
        for (int j = 0; j < 4; ++j)
            atomicAdd(&prop[(size_t)(k0 + j)*HID + gcol], acc[mf][j]);
    }
}

// -------------------------------------------------------------------------
// K3: blocks 0..31 = zz+loss;  blocks 32..35 = proto scatter-update
// -------------------------------------------------------------------------
__global__ __launch_bounds__(256) void k_zzproto(
        const unsigned short* __restrict__ v_bf, const unsigned short* __restrict__ P0_bf,
        const unsigned short* __restrict__ S_bf, float* __restrict__ lossAcc,
        const float* __restrict__ P0, const float* __restrict__ prop,
        const int* __restrict__ rowflag, const int* __restrict__ cntRow,
        const int* __restrict__ rowOwner_g, float* __restrict__ protoOut)
{
    __shared__ unsigned short sh[16*128 + 128*128];
    __shared__ float red[256];
    __shared__ float nActS[32];
    __shared__ int kS[32];
    int bid = blockIdx.x, t = threadIdx.x;
    int wave = t >> 6, lane = t & 63;

    if (bid < 32) {
        // ---- zz + CE loss ----
        int ms = bid;
        unsigned short* AS  = sh;
        unsigned short* BS2 = sh + 16*128;
        f32x4 acc[2] = {{0.f,0.f,0.f,0.f},{0.f,0.f,0.f,0.f}};
        for (int ht = 0; ht < 6; ++ht) {
            int h0 = ht * 128;
            __syncthreads();
            {
                int row = t >> 4, c = t & 15;
                *(uint4*)&AS[row*128 + (c ^ (row & 7))*8] =
                    *(const uint4*)&v_bf[(size_t)(ms*16 + row)*HID + h0 + c*8];
                #pragma unroll
                for (int q = 0; q < 8; ++q) {
                    int j2 = t + q*256;
                    int prow = j2 >> 4, c2 = j2 & 15;
                    *(uint4*)&BS2[prow*128 + (c2 ^ (prow & 7))*8] =
                        *(const uint4*)&P0_bf[(size_t)prow*HID + h0 + c2*8];
                }
            }
            __syncthreads();
            int arow = lane & 15;
            #pragma unroll
            for (int kk = 0; kk < 4; ++kk) {
                int cA = (kk*4 + (lane >> 4)) ^ (arow & 7);
                bf16x8 a = *(const bf16x8*)&AS[arow*128 + cA*8];
                #pragma unroll
                for (int nf = 0; nf < 2; ++nf) {
                    int brow = wave*32 + nf*16 + (lane & 15);
                    int cB = (kk*4 + (lane >> 4)) ^ (brow & 7);
                    bf16x8 b = *(const bf16x8*)&BS2[brow*128 + cB*8];
                    acc[nf] = __builtin_amdgcn_mfma_f32_16x16x32_bf16(a, b, acc[nf], 0, 0, 0);
                }
            }
        }
        float term = 0.f;
        #pragma unroll
        for (int nf = 0; nf < 2; ++nf) {
            int p = wave*32 + nf*16 + (lane & 15);
            int kr0 = ms*16 + (lane >> 4) * 4;
            #pragma unroll
            for (int j = 0; j < 4; ++j) {
                float S = bf2f(S_bf[(size_t)(kr0 + j)*128 + p]);
                if (S != 0.f) {
                    float z = acc[nf][j];
                    float s = 1.f / (1.f + expf(-z));
                    term += S * (logf(expf(1.f - s) + expf(s)) - s);
                }
            }
        }
        red[t] = term;
        __syncthreads();
        for (int off = 128; off; off >>= 1) {
            if (t < off) red[t] += red[t + off];
            __syncthreads();
        }
        if (t == 0) atomicAdd(lossAcc, red[0]);
    } else {
        // ---- proto scatter-update, 32 p-rows per block ----
        int base = (bid - 32) * 32;
        if (t < 32) {
            int p = base + t;
            int k = rowOwner_g[p];
            float n = 0.f;
            if (k >= 0)
                for (int i = 0; i < 16; ++i) {
                    int rr = k*NRELD + i;
                    if (rowflag[rr]) n += (float)cntRow[rr];
                }
            nActS[t] = n; kS[t] = k;
        }
        __syncthreads();
        for (int j = 0; j < 24; ++j) {
            int flat = t + 256*j;                 // 32 rows x 192 float4
            int pl = flat / 192, c = flat % 192;
            int p = base + pl;
            float4 old = *(const float4*)&P0[(size_t)p*HID + c*4];
            float4 o = old;
            int k = kS[pl]; float n = nActS[pl];
            if (k >= 0 && n > 0.f) {
                float4 pr = *(const float4*)&prop[(size_t)k*HID + c*4];
                float invn = 0.5f / n;
                o.x = 0.5f*old.x + pr.x*invn;
                o.y = 0.5f*old.y + pr.y*invn;
                o.z = 0.5f*old.z + pr.z*invn;
                o.w = 0.5f*old.w + pr.w*invn;
            }
            *(float4*)&protoOut[(size_t)p*HID + c*4] = o;
        }
    }
}

// -------------------------------------------------------------------------
// K4: logits[b,p] = -||inst[b]-proto[p]||^2 ; block 0 finalizes loss
// -------------------------------------------------------------------------
__global__ __launch_bounds__(128) void k_logits(const float* __restrict__ inst,
        const float* __restrict__ protoOut, const float* __restrict__ lossAcc,
        const int* __restrict__ rowflag, const int* __restrict__ cntRow,
        float* __restrict__ outLogits, float* __restrict__ outLoss)
{
    int b = blockIdx.x, t = threadIdx.x;
    __shared__ float iS[768];
    __shared__ float ls[128];
    __shared__ int ts[128];
    for (int q = 0; q < 6; ++q) iS[t + 128*q] = inst[(size_t)b*HID + t + 128*q];
    __syncthreads();
    const float4* pr = (const float4*)&protoOut[(size_t)t*HID];
    float acc = 0.f;
    for (int q = 0; q < HID/4; ++q) {
        float4 pv = pr[q];
        float dx = iS[q*4+0] - pv.x, dy = iS[q*4+1] - pv.y;
        float dz = iS[q*4+2] - pv.z, dw = iS[q*4+3] - pv.w;
        acc += dx*dx + dy*dy + dz*dz + dw*dw;
    }
    outLogits[b*PSZ + t] = -acc;
    if (b == 0) {
        float s = 0.f; int tot = 0;
        #pragma unroll
        for (int q = 0; q < 4; ++q) {
            int rr = t + 128*q;
            int rf = rowflag[rr];
            tot |= rf;
            if (rf) s += (float)cntRow[rr];
        }
        ls[t] = s; ts[t] = tot;
        __syncthreads();
        for (int off = 64; off; off >>= 1) {
            if (t < off) { ls[t] += ls[t + off]; ts[t] |= ts[t + off]; }
            __syncthreads();
        }
        if (t == 0)
            outLoss[0] = ts[0]
                ? (lossAcc[0] + (65536.f - ls[0]) * 0.6931471805599453f) * (1.f/65536.f)
                : 0.f;
    }
}

// -------------------------------------------------------------------------
extern "C" void kernel_launch(void* const* d_in, const int* in_sizes, int n_in,
                              void* d_out, int out_size, void* d_ws, size_t ws_size,
                              hipStream_t stream)
{
    const float* inst  = (const float*)d_in[0];   // [32,768]
    const float* rel   = (const float*)d_in[1];   // [16,768,768]
    const int* relIds  = (const int*)d_in[2];     // [32,16,128]
    const int* labels  = (const int*)d_in[3];     // [32]
    const float* P0    = (const float*)d_in[4];   // [128,768]
    float* out = (float*)d_out;
    float* outLogits = out;            // 4096
    float* outLoss   = out + 4096;     // 1
    float* outProto  = out + 4097;     // 98304

    char* ws = (char*)d_ws;
    unsigned short* v_bf    = (unsigned short*)(ws + 0);        // 786432 B
    unsigned short* w_bf    = (unsigned short*)(ws + 786432);   // 786432 B
    unsigned short* S_bf    = (unsigned short*)(ws + 1572864);  // 131072 B
    unsigned short* P0_bf   = (unsigned short*)(ws + 1703936);  // 196608 B
    unsigned short* P0T_bf  = (unsigned short*)(ws + 1900544);  // 196608 B
    unsigned short* pt_bf   = (unsigned short*)(ws + 2097152);  // 49152 B
    float* prop    = (float*)(ws + 2146304);                    // 98304 B
    float* lossAcc = (float*)(ws + 2244608);                    // 128 B
    int*   rowflag = (int*)(ws + 2244736);                      // 2048 B
    int*   cntRow  = (int*)(ws + 2246784);                      // 2048 B
    int*   rowOwner= (int*)(ws + 2248832);                      // 512 B

    k_prep<<<512, 192, 0, stream>>>(labels, relIds, P0, S_bf, P0_bf, P0T_bf,
                                    pt_bf, rowflag, cntRow, rowOwner);
    k_vw<<<288, 256, 0, stream>>>(rel, pt_bf, S_bf, P0T_bf, v_bf, w_bf,
                                  prop, lossAcc);
    k_prop_mfma<<<dim3(16,12), 256, 0, stream>>>(rel, w_bf, prop);
    k_zzproto<<<36, 256, 0, stream>>>(v_bf, P0_bf, S_bf, lossAcc, P0, prop,
                                      rowflag, cntRow, rowOwner, outProto);
    k_logits<<<32, 128, 0, stream>>>(inst, outProto, lossAcc, rowflag, cntRow,
                                     outLogits, outLoss);
}